// Round 1
// baseline (2776.091 us; speedup 1.0000x reference)
//
#include <hip/hip_runtime.h>
#include <math.h>

#define N_NODES 10000
#define N_EDGES 320000
#define D 256
#define NEG_SLOPE 0.2f

// ---- float <-> ordered-int mapping for atomicMax on floats ----
__device__ __forceinline__ int f2oi(float f) {
  int i = __float_as_int(f);
  return (i >= 0) ? i : (i ^ 0x7FFFFFFF);
}
__device__ __forceinline__ float oi2f(int i) {
  return __int_as_float((i >= 0) ? i : (i ^ 0x7FFFFFFF));
}

// out[n][d] = b_fc[d]  (d_out is poisoned 0xAA before every timed call)
__global__ void init_out_kernel(float* __restrict__ out, const float* __restrict__ b_fc) {
  int i = blockIdx.x * blockDim.x + threadIdx.x;
  if (i < N_NODES * D) out[i] = b_fc[i & (D - 1)];
}

__global__ void init_stats_kernel(int* __restrict__ m_int, float* __restrict__ denom) {
  int i = blockIdx.x * blockDim.x + threadIdx.x;
  if (i < N_NODES) {
    m_int[i] = f2oi(-INFINITY);
    denom[i] = 0.0f;
  }
}

// Triple GEMM: ps = feat@Ws.T, pt = feat@Wt.T, fcp = feat@Wfc.T
// block = one node, thread t = output dim t. Feature row staged in LDS
// (broadcast reads), W rows streamed via float4 (L2-resident, 768 KB total).
__global__ void proj_kernel(const float* __restrict__ feat,
                            const float* __restrict__ Ws,
                            const float* __restrict__ Wt,
                            const float* __restrict__ Wfc,
                            float* __restrict__ ps, float* __restrict__ pt,
                            float* __restrict__ fcp) {
  __shared__ float f[D];
  const int n = blockIdx.x;
  const int t = threadIdx.x;
  f[t] = feat[n * D + t];
  __syncthreads();
  const float4* ws4 = (const float4*)(Ws + t * D);
  const float4* wt4 = (const float4*)(Wt + t * D);
  const float4* wf4 = (const float4*)(Wfc + t * D);
  const float4* f4 = (const float4*)f;
  float as = 0.f, at = 0.f, af = 0.f;
#pragma unroll 8
  for (int k = 0; k < D / 4; ++k) {
    float4 fv = f4[k];
    float4 a = ws4[k];
    float4 b = wt4[k];
    float4 c = wf4[k];
    as += fv.x * a.x + fv.y * a.y + fv.z * a.z + fv.w * a.w;
    at += fv.x * b.x + fv.y * b.y + fv.z * b.z + fv.w * b.w;
    af += fv.x * c.x + fv.y * c.y + fv.z * c.z + fv.w * c.w;
  }
  ps[n * D + t] = as;
  pt[n * D + t] = at;
  fcp[n * D + t] = af;
}

// One wave (64 lanes) per edge: lane holds dims [4*lane, 4*lane+4).
// e = W_attn . lrelu(ps[src] + pt[dst]); segment max into m_int[src].
__global__ void edge_logit_kernel(const float* __restrict__ ps,
                                  const float* __restrict__ pt,
                                  const int* __restrict__ src,
                                  const int* __restrict__ dst,
                                  const float* __restrict__ Wattn,
                                  float* __restrict__ e,
                                  int* __restrict__ m_int) {
  const int edge = blockIdx.x * 4 + (threadIdx.x >> 6);
  const int lane = threadIdx.x & 63;
  if (edge >= N_EDGES) return;
  const int s = src[edge], t = dst[edge];
  float4 a = *(const float4*)(ps + s * D + lane * 4);
  float4 b = *(const float4*)(pt + t * D + lane * 4);
  float4 w = *(const float4*)(Wattn + lane * 4);
  float sum = 0.f, z;
  z = a.x + b.x; z = (z >= 0.f) ? z : NEG_SLOPE * z; sum += w.x * z;
  z = a.y + b.y; z = (z >= 0.f) ? z : NEG_SLOPE * z; sum += w.y * z;
  z = a.z + b.z; z = (z >= 0.f) ? z : NEG_SLOPE * z; sum += w.z * z;
  z = a.w + b.w; z = (z >= 0.f) ? z : NEG_SLOPE * z; sum += w.w * z;
#pragma unroll
  for (int off = 32; off > 0; off >>= 1) sum += __shfl_down(sum, off, 64);
  if (lane == 0) {
    e[edge] = sum;
    atomicMax(&m_int[s], f2oi(sum));
  }
}

// expv = exp(e - m[src]);  denom[src] += expv
__global__ void edge_exp_kernel(const float* __restrict__ e,
                                const int* __restrict__ src,
                                const int* __restrict__ m_int,
                                float* __restrict__ expv,
                                float* __restrict__ denom) {
  const int i = blockIdx.x * blockDim.x + threadIdx.x;
  if (i >= N_EDGES) return;
  const int s = src[i];
  float ex = __expf(e[i] - oi2f(m_int[s]));
  expv[i] = ex;
  atomicAdd(&denom[s], ex);
}

// out[dst] += (expv/denom[src]) * fcp[src]   (wave per edge, 4 dims/lane)
__global__ void scatter_kernel(const float* __restrict__ fcp,
                               const int* __restrict__ src,
                               const int* __restrict__ dst,
                               const float* __restrict__ expv,
                               const float* __restrict__ denom,
                               float* __restrict__ out) {
  const int edge = blockIdx.x * 4 + (threadIdx.x >> 6);
  const int lane = threadIdx.x & 63;
  if (edge >= N_EDGES) return;
  const int s = src[edge], t = dst[edge];
  const float alpha = expv[edge] / denom[s];
  float4 fv = *(const float4*)(fcp + s * D + lane * 4);
  float* o = out + t * D + lane * 4;
  atomicAdd(o + 0, alpha * fv.x);
  atomicAdd(o + 1, alpha * fv.y);
  atomicAdd(o + 2, alpha * fv.z);
  atomicAdd(o + 3, alpha * fv.w);
}

extern "C" void kernel_launch(void* const* d_in, const int* in_sizes, int n_in,
                              void* d_out, int out_size, void* d_ws, size_t ws_size,
                              hipStream_t stream) {
  const float* feat  = (const float*)d_in[0];
  const int*   src   = (const int*)d_in[1];
  const int*   dst   = (const int*)d_in[2];
  const float* Ws    = (const float*)d_in[3];
  const float* Wt    = (const float*)d_in[4];
  const float* Wattn = (const float*)d_in[5];
  const float* Wfc   = (const float*)d_in[6];
  const float* bfc   = (const float*)d_in[7];
  float* out = (float*)d_out;

  // workspace layout (fp32 elems): ps | pt | fcp | e | expv | denom | m_int
  float* ws_f = (float*)d_ws;
  float* ps    = ws_f;
  float* pt    = ps + (size_t)N_NODES * D;
  float* fcp   = pt + (size_t)N_NODES * D;
  float* e     = fcp + (size_t)N_NODES * D;
  float* expv  = e + N_EDGES;
  float* denom = expv + N_EDGES;
  int*   m_int = (int*)(denom + N_NODES);

  init_out_kernel<<<(N_NODES * D + 255) / 256, 256, 0, stream>>>(out, bfc);
  init_stats_kernel<<<(N_NODES + 255) / 256, 256, 0, stream>>>(m_int, denom);
  proj_kernel<<<N_NODES, 256, 0, stream>>>(feat, Ws, Wt, Wfc, ps, pt, fcp);
  edge_logit_kernel<<<(N_EDGES + 3) / 4, 256, 0, stream>>>(ps, pt, src, dst, Wattn, e, m_int);
  edge_exp_kernel<<<(N_EDGES + 255) / 256, 256, 0, stream>>>(e, src, m_int, expv, denom);
  scatter_kernel<<<(N_EDGES + 3) / 4, 256, 0, stream>>>(fcp, src, dst, expv, denom, out);
}

// Round 2
// 1310.958 us; speedup vs baseline: 2.1176x; 2.1176x over previous
//
#include <hip/hip_runtime.h>
#include <math.h>

#define N_NODES 10000
#define N_EDGES 320000
#define D 256
#define NEG_SLOPE 0.2f

// ---- float <-> ordered-int mapping for atomicMax on floats ----
__device__ __forceinline__ int f2oi(float f) {
  int i = __float_as_int(f);
  return (i >= 0) ? i : (i ^ 0x7FFFFFFF);
}
__device__ __forceinline__ float oi2f(int i) {
  return __int_as_float((i >= 0) ? i : (i ^ 0x7FFFFFFF));
}

// out[n][d] = b_fc[d]  (d_out is poisoned 0xAA before every timed call)
__global__ void init_out_kernel(float* __restrict__ out, const float* __restrict__ b_fc) {
  int i = blockIdx.x * blockDim.x + threadIdx.x;
  if (i < N_NODES * D) out[i] = b_fc[i & (D - 1)];
}

__global__ void init_stats_kernel(int* __restrict__ m_int, float* __restrict__ denom) {
  int i = blockIdx.x * blockDim.x + threadIdx.x;
  if (i < N_NODES) {
    m_int[i] = f2oi(-INFINITY);
    denom[i] = 0.0f;
  }
}

// Tiled GEMM: C[10000 x 768] = feat[10000 x 256] @ [Ws;Wt;Wfc]^T
// BM=BN=64, BK=32, 256 threads, 4x4 microtile/thread.
// A,B tiles stored TRANSPOSED in LDS ([k][m], pad +4) so compute reads are
// contiguous float4 along m/n (conflict-free / 2-way-free).
__global__ __launch_bounds__(256) void proj_gemm_kernel(
    const float* __restrict__ feat,
    const float* __restrict__ Ws,
    const float* __restrict__ Wt,
    const float* __restrict__ Wfc,
    float* __restrict__ ps, float* __restrict__ pt, float* __restrict__ fcp) {
  __shared__ float As[32][68];
  __shared__ float Bs[32][68];
  const int mt = blockIdx.x;       // node tile: rows mt*64..
  const int nt = blockIdx.y;       // 0..11: 4 tiles each for Ws, Wt, Wfc
  const int tid = threadIdx.x;

  const float* W = (nt < 4) ? Ws : ((nt < 8) ? Wt : Wfc);
  float* outp    = (nt < 4) ? ps : ((nt < 8) ? pt : fcp);
  const int ncol0 = (nt & 3) * 64;   // column offset within the 256-col output
  const int row0 = mt * 64;

  // staging coords: 8 float4-lanes per row, 32 rows per pass, 2 passes
  const int lrow = tid >> 3;          // 0..31
  const int lcol = (tid & 7) * 4;     // 0,4,...,28

  const int tx = tid & 15;            // output col group
  const int ty = tid >> 4;            // output row group
  float acc[4][4] = {{0.f}};

  for (int k0 = 0; k0 < D; k0 += 32) {
#pragma unroll
    for (int p = 0; p < 2; ++p) {
      const int r = lrow + p * 32;
      const int gr = row0 + r;
      float4 v = make_float4(0.f, 0.f, 0.f, 0.f);
      if (gr < N_NODES) v = *(const float4*)(feat + (size_t)gr * D + k0 + lcol);
      As[lcol + 0][r] = v.x; As[lcol + 1][r] = v.y;
      As[lcol + 2][r] = v.z; As[lcol + 3][r] = v.w;
      float4 w = *(const float4*)(W + (size_t)(ncol0 + r) * D + k0 + lcol);
      Bs[lcol + 0][r] = w.x; Bs[lcol + 1][r] = w.y;
      Bs[lcol + 2][r] = w.z; Bs[lcol + 3][r] = w.w;
    }
    __syncthreads();
#pragma unroll
    for (int k = 0; k < 32; ++k) {
      const float4 av = *(const float4*)&As[k][ty * 4];
      const float4 bv = *(const float4*)&Bs[k][tx * 4];
      acc[0][0] += av.x * bv.x; acc[0][1] += av.x * bv.y;
      acc[0][2] += av.x * bv.z; acc[0][3] += av.x * bv.w;
      acc[1][0] += av.y * bv.x; acc[1][1] += av.y * bv.y;
      acc[1][2] += av.y * bv.z; acc[1][3] += av.y * bv.w;
      acc[2][0] += av.z * bv.x; acc[2][1] += av.z * bv.y;
      acc[2][2] += av.z * bv.z; acc[2][3] += av.z * bv.w;
      acc[3][0] += av.w * bv.x; acc[3][1] += av.w * bv.y;
      acc[3][2] += av.w * bv.z; acc[3][3] += av.w * bv.w;
    }
    __syncthreads();
  }

#pragma unroll
  for (int i = 0; i < 4; ++i) {
    const int gr = row0 + ty * 4 + i;
    if (gr < N_NODES) {
      float4 v = make_float4(acc[i][0], acc[i][1], acc[i][2], acc[i][3]);
      *(float4*)(outp + (size_t)gr * D + ncol0 + tx * 4) = v;
    }
  }
}

// One wave (64 lanes) per edge: lane holds dims [4*lane, 4*lane+4).
// e = W_attn . lrelu(ps[src] + pt[dst]); segment max into m_int[src].
__global__ void edge_logit_kernel(const float* __restrict__ ps,
                                  const float* __restrict__ pt,
                                  const int* __restrict__ src,
                                  const int* __restrict__ dst,
                                  const float* __restrict__ Wattn,
                                  float* __restrict__ e,
                                  int* __restrict__ m_int) {
  const int edge = blockIdx.x * 4 + (threadIdx.x >> 6);
  const int lane = threadIdx.x & 63;
  if (edge >= N_EDGES) return;
  const int s = src[edge], t = dst[edge];
  float4 a = *(const float4*)(ps + (size_t)s * D + lane * 4);
  float4 b = *(const float4*)(pt + (size_t)t * D + lane * 4);
  float4 w = *(const float4*)(Wattn + lane * 4);
  float sum = 0.f, z;
  z = a.x + b.x; z = (z >= 0.f) ? z : NEG_SLOPE * z; sum += w.x * z;
  z = a.y + b.y; z = (z >= 0.f) ? z : NEG_SLOPE * z; sum += w.y * z;
  z = a.z + b.z; z = (z >= 0.f) ? z : NEG_SLOPE * z; sum += w.z * z;
  z = a.w + b.w; z = (z >= 0.f) ? z : NEG_SLOPE * z; sum += w.w * z;
#pragma unroll
  for (int off = 32; off > 0; off >>= 1) sum += __shfl_down(sum, off, 64);
  if (lane == 0) {
    e[edge] = sum;
    atomicMax(&m_int[s], f2oi(sum));
  }
}

// expv = exp(e - m[src]);  denom[src] += expv
__global__ void edge_exp_kernel(const float* __restrict__ e,
                                const int* __restrict__ src,
                                const int* __restrict__ m_int,
                                float* __restrict__ expv,
                                float* __restrict__ denom) {
  const int i = blockIdx.x * blockDim.x + threadIdx.x;
  if (i >= N_EDGES) return;
  const int s = src[i];
  float ex = __expf(e[i] - oi2f(m_int[s]));
  expv[i] = ex;
  atomicAdd(&denom[s], ex);
}

// out[dst] += (expv/denom[src]) * fcp[src]   (wave per edge, 4 dims/lane)
__global__ void scatter_kernel(const float* __restrict__ fcp,
                               const int* __restrict__ src,
                               const int* __restrict__ dst,
                               const float* __restrict__ expv,
                               const float* __restrict__ denom,
                               float* __restrict__ out) {
  const int edge = blockIdx.x * 4 + (threadIdx.x >> 6);
  const int lane = threadIdx.x & 63;
  if (edge >= N_EDGES) return;
  const int s = src[edge], t = dst[edge];
  const float alpha = expv[edge] / denom[s];
  float4 fv = *(const float4*)(fcp + (size_t)s * D + lane * 4);
  float* o = out + (size_t)t * D + lane * 4;
  atomicAdd(o + 0, alpha * fv.x);
  atomicAdd(o + 1, alpha * fv.y);
  atomicAdd(o + 2, alpha * fv.z);
  atomicAdd(o + 3, alpha * fv.w);
}

extern "C" void kernel_launch(void* const* d_in, const int* in_sizes, int n_in,
                              void* d_out, int out_size, void* d_ws, size_t ws_size,
                              hipStream_t stream) {
  const float* feat  = (const float*)d_in[0];
  const int*   src   = (const int*)d_in[1];
  const int*   dst   = (const int*)d_in[2];
  const float* Ws    = (const float*)d_in[3];
  const float* Wt    = (const float*)d_in[4];
  const float* Wattn = (const float*)d_in[5];
  const float* Wfc   = (const float*)d_in[6];
  const float* bfc   = (const float*)d_in[7];
  float* out = (float*)d_out;

  // workspace layout (fp32 elems): ps | pt | fcp | e | expv | denom | m_int
  float* ws_f = (float*)d_ws;
  float* ps    = ws_f;
  float* pt    = ps + (size_t)N_NODES * D;
  float* fcp   = pt + (size_t)N_NODES * D;
  float* e     = fcp + (size_t)N_NODES * D;
  float* expv  = e + N_EDGES;
  float* denom = expv + N_EDGES;
  int*   m_int = (int*)(denom + N_NODES);

  init_out_kernel<<<(N_NODES * D + 255) / 256, 256, 0, stream>>>(out, bfc);
  init_stats_kernel<<<(N_NODES + 255) / 256, 256, 0, stream>>>(m_int, denom);
  dim3 pg((N_NODES + 63) / 64, 12);
  proj_gemm_kernel<<<pg, 256, 0, stream>>>(feat, Ws, Wt, Wfc, ps, pt, fcp);
  edge_logit_kernel<<<(N_EDGES + 3) / 4, 256, 0, stream>>>(ps, pt, src, dst, Wattn, e, m_int);
  edge_exp_kernel<<<(N_EDGES + 255) / 256, 256, 0, stream>>>(e, src, m_int, expv, denom);
  scatter_kernel<<<(N_EDGES + 3) / 4, 256, 0, stream>>>(fcp, src, dst, expv, denom, out);
}

// Round 3
// 341.506 us; speedup vs baseline: 8.1290x; 3.8388x over previous
//
#include <hip/hip_runtime.h>
#include <math.h>

#define N_NODES 10000
#define N_EDGES 320000
#define D 256
#define NEG_SLOPE 0.2f

// ---- float <-> ordered-int mapping for atomicMax on floats ----
__device__ __forceinline__ int f2oi(float f) {
  int i = __float_as_int(f);
  return (i >= 0) ? i : (i ^ 0x7FFFFFFF);
}
__device__ __forceinline__ float oi2f(int i) {
  return __int_as_float((i >= 0) ? i : (i ^ 0x7FFFFFFF));
}

// m_int = -inf (ordered-int), denom = 0, deg = 0
__global__ void init_stats_kernel(int* __restrict__ m_int, float* __restrict__ denom,
                                  int* __restrict__ deg) {
  int i = blockIdx.x * blockDim.x + threadIdx.x;
  if (i < N_NODES) {
    m_int[i] = f2oi(-INFINITY);
    denom[i] = 0.0f;
    deg[i] = 0;
  }
}

// Tiled GEMM: C[10000 x 768] = feat[10000 x 256] @ [Ws;Wt;Wfc]^T
// BM=BN=64, BK=32, 256 threads, 4x4 microtile/thread.
__global__ __launch_bounds__(256) void proj_gemm_kernel(
    const float* __restrict__ feat,
    const float* __restrict__ Ws,
    const float* __restrict__ Wt,
    const float* __restrict__ Wfc,
    float* __restrict__ ps, float* __restrict__ pt, float* __restrict__ fcp) {
  __shared__ float As[32][68];
  __shared__ float Bs[32][68];
  const int mt = blockIdx.x;
  const int nt = blockIdx.y;       // 0..11: 4 tiles each for Ws, Wt, Wfc
  const int tid = threadIdx.x;

  const float* W = (nt < 4) ? Ws : ((nt < 8) ? Wt : Wfc);
  float* outp    = (nt < 4) ? ps : ((nt < 8) ? pt : fcp);
  const int ncol0 = (nt & 3) * 64;
  const int row0 = mt * 64;

  const int lrow = tid >> 3;          // 0..31
  const int lcol = (tid & 7) * 4;     // 0,4,...,28
  const int tx = tid & 15;
  const int ty = tid >> 4;
  float acc[4][4] = {{0.f}};

  for (int k0 = 0; k0 < D; k0 += 32) {
#pragma unroll
    for (int p = 0; p < 2; ++p) {
      const int r = lrow + p * 32;
      const int gr = row0 + r;
      float4 v = make_float4(0.f, 0.f, 0.f, 0.f);
      if (gr < N_NODES) v = *(const float4*)(feat + (size_t)gr * D + k0 + lcol);
      As[lcol + 0][r] = v.x; As[lcol + 1][r] = v.y;
      As[lcol + 2][r] = v.z; As[lcol + 3][r] = v.w;
      float4 w = *(const float4*)(W + (size_t)(ncol0 + r) * D + k0 + lcol);
      Bs[lcol + 0][r] = w.x; Bs[lcol + 1][r] = w.y;
      Bs[lcol + 2][r] = w.z; Bs[lcol + 3][r] = w.w;
    }
    __syncthreads();
#pragma unroll
    for (int k = 0; k < 32; ++k) {
      const float4 av = *(const float4*)&As[k][ty * 4];
      const float4 bv = *(const float4*)&Bs[k][tx * 4];
      acc[0][0] += av.x * bv.x; acc[0][1] += av.x * bv.y;
      acc[0][2] += av.x * bv.z; acc[0][3] += av.x * bv.w;
      acc[1][0] += av.y * bv.x; acc[1][1] += av.y * bv.y;
      acc[1][2] += av.y * bv.z; acc[1][3] += av.y * bv.w;
      acc[2][0] += av.z * bv.x; acc[2][1] += av.z * bv.y;
      acc[2][2] += av.z * bv.z; acc[2][3] += av.z * bv.w;
      acc[3][0] += av.w * bv.x; acc[3][1] += av.w * bv.y;
      acc[3][2] += av.w * bv.z; acc[3][3] += av.w * bv.w;
    }
    __syncthreads();
  }

#pragma unroll
  for (int i = 0; i < 4; ++i) {
    const int gr = row0 + ty * 4 + i;
    if (gr < N_NODES) {
      float4 v = make_float4(acc[i][0], acc[i][1], acc[i][2], acc[i][3]);
      *(float4*)(outp + (size_t)gr * D + ncol0 + tx * 4) = v;
    }
  }
}

// One wave per edge: e = W_attn . lrelu(ps[src] + pt[dst]); segment max into
// m_int[src]; also counts dst-degree histogram (lane 0).
__global__ void edge_logit_kernel(const float* __restrict__ ps,
                                  const float* __restrict__ pt,
                                  const int* __restrict__ src,
                                  const int* __restrict__ dst,
                                  const float* __restrict__ Wattn,
                                  float* __restrict__ e,
                                  int* __restrict__ m_int,
                                  int* __restrict__ deg) {
  const int edge = blockIdx.x * 4 + (threadIdx.x >> 6);
  const int lane = threadIdx.x & 63;
  if (edge >= N_EDGES) return;
  const int s = src[edge], t = dst[edge];
  float4 a = *(const float4*)(ps + (size_t)s * D + lane * 4);
  float4 b = *(const float4*)(pt + (size_t)t * D + lane * 4);
  float4 w = *(const float4*)(Wattn + lane * 4);
  float sum = 0.f, z;
  z = a.x + b.x; z = (z >= 0.f) ? z : NEG_SLOPE * z; sum += w.x * z;
  z = a.y + b.y; z = (z >= 0.f) ? z : NEG_SLOPE * z; sum += w.y * z;
  z = a.z + b.z; z = (z >= 0.f) ? z : NEG_SLOPE * z; sum += w.z * z;
  z = a.w + b.w; z = (z >= 0.f) ? z : NEG_SLOPE * z; sum += w.w * z;
#pragma unroll
  for (int off = 32; off > 0; off >>= 1) sum += __shfl_down(sum, off, 64);
  if (lane == 0) {
    e[edge] = sum;
    atomicMax(&m_int[s], f2oi(sum));
    atomicAdd(&deg[t], 1);
  }
}

// expv = exp(e - m[src]);  denom[src] += expv
__global__ void edge_exp_kernel(const float* __restrict__ e,
                                const int* __restrict__ src,
                                const int* __restrict__ m_int,
                                float* __restrict__ expv,
                                float* __restrict__ denom) {
  const int i = blockIdx.x * blockDim.x + threadIdx.x;
  if (i >= N_EDGES) return;
  const int s = src[i];
  float ex = __expf(e[i] - oi2f(m_int[s]));
  expv[i] = ex;
  atomicAdd(&denom[s], ex);
}

// Single-block exclusive scan of deg[10000] -> ofs[10001], cursor = ofs.
#define SCAN_T 256
#define CHUNK 40   // 256*40 = 10240 >= N_NODES
__global__ __launch_bounds__(SCAN_T) void scan_kernel(const int* __restrict__ deg,
                                                      int* __restrict__ ofs,
                                                      int* __restrict__ cursor) {
  __shared__ int sv[N_NODES];
  __shared__ int part[SCAN_T];
  const int t = threadIdx.x;
  for (int i = t; i < N_NODES; i += SCAN_T) sv[i] = deg[i];
  __syncthreads();
  const int base = t * CHUNK;
  int sum = 0;
#pragma unroll
  for (int i = 0; i < CHUNK; ++i) {
    int idx = base + i;
    if (idx < N_NODES) {
      int v = sv[idx];
      sv[idx] = sum;     // chunk-exclusive
      sum += v;
    }
  }
  part[t] = sum;
  __syncthreads();
  for (int off = 1; off < SCAN_T; off <<= 1) {
    int v = (t >= off) ? part[t - off] : 0;
    __syncthreads();
    part[t] += v;
    __syncthreads();
  }
  for (int i = t; i < N_NODES; i += SCAN_T) {
    int c = i / CHUNK;
    int o = sv[i] + (c ? part[c - 1] : 0);
    ofs[i] = o;
    cursor[i] = o;
  }
  if (t == 0) ofs[N_NODES] = part[SCAN_T - 1];
}

// Bucket edges by dst; store src id and alpha directly in bucket order.
__global__ void fill_kernel(const int* __restrict__ src,
                            const int* __restrict__ dst,
                            const float* __restrict__ expv,
                            const float* __restrict__ denom,
                            int* __restrict__ cursor,
                            int* __restrict__ src_b,
                            float* __restrict__ alpha_b) {
  const int i = blockIdx.x * blockDim.x + threadIdx.x;
  if (i >= N_EDGES) return;
  const int dnode = dst[i];
  const int p = atomicAdd(&cursor[dnode], 1);
  const int s = src[i];
  src_b[p] = s;
  alpha_b[p] = expv[i] / denom[s];
}

// Block per dst node; thread d owns output dim d. Gather-accumulate, one write.
__global__ __launch_bounds__(256) void gather_agg_kernel(
    const float* __restrict__ fcp,
    const int* __restrict__ src_b,
    const float* __restrict__ alpha_b,
    const int* __restrict__ ofs,
    const float* __restrict__ b_fc,
    float* __restrict__ out) {
  const int n = blockIdx.x;
  const int d = threadIdx.x;
  const int beg = ofs[n], end = ofs[n + 1];
  float acc = 0.f;
  for (int j = beg; j < end; ++j) {
    const int s = src_b[j];
    const float a = alpha_b[j];
    acc += a * fcp[(size_t)s * D + d];
  }
  out[(size_t)n * D + d] = acc + b_fc[d];
}

extern "C" void kernel_launch(void* const* d_in, const int* in_sizes, int n_in,
                              void* d_out, int out_size, void* d_ws, size_t ws_size,
                              hipStream_t stream) {
  const float* feat  = (const float*)d_in[0];
  const int*   src   = (const int*)d_in[1];
  const int*   dst   = (const int*)d_in[2];
  const float* Ws    = (const float*)d_in[3];
  const float* Wt    = (const float*)d_in[4];
  const float* Wattn = (const float*)d_in[5];
  const float* Wfc   = (const float*)d_in[6];
  const float* bfc   = (const float*)d_in[7];
  float* out = (float*)d_out;

  // workspace layout (fp32 elems):
  // ps | pt | fcp | e/expv | alpha_b | src_b | denom | m_int | deg | ofs | cursor
  float* ws_f = (float*)d_ws;
  float* ps      = ws_f;
  float* pt      = ps + (size_t)N_NODES * D;
  float* fcp     = pt + (size_t)N_NODES * D;
  float* e       = fcp + (size_t)N_NODES * D;   // reused as expv target below
  float* expv    = e + N_EDGES;
  float* alpha_b = expv + N_EDGES;
  int*   src_b   = (int*)(alpha_b + N_EDGES);
  float* denom   = (float*)(src_b + N_EDGES);
  int*   m_int   = (int*)(denom + N_NODES);
  int*   deg     = m_int + N_NODES;
  int*   ofs     = deg + N_NODES;               // N_NODES+1
  int*   cursor  = ofs + N_NODES + 1;

  init_stats_kernel<<<(N_NODES + 255) / 256, 256, 0, stream>>>(m_int, denom, deg);
  dim3 pg((N_NODES + 63) / 64, 12);
  proj_gemm_kernel<<<pg, 256, 0, stream>>>(feat, Ws, Wt, Wfc, ps, pt, fcp);
  edge_logit_kernel<<<(N_EDGES + 3) / 4, 256, 0, stream>>>(ps, pt, src, dst, Wattn, e, m_int, deg);
  edge_exp_kernel<<<(N_EDGES + 255) / 256, 256, 0, stream>>>(e, src, m_int, expv, denom);
  scan_kernel<<<1, SCAN_T, 0, stream>>>(deg, ofs, cursor);
  fill_kernel<<<(N_EDGES + 255) / 256, 256, 0, stream>>>(src, dst, expv, denom, cursor, src_b, alpha_b);
  gather_agg_kernel<<<N_NODES, 256, 0, stream>>>(fcp, src_b, alpha_b, ofs, bfc, out);
}

// Round 4
// 270.427 us; speedup vs baseline: 10.2656x; 1.2628x over previous
//
#include <hip/hip_runtime.h>
#include <math.h>

#define N_NODES 10000
#define N_EDGES 320000
#define D 256
#define NEG_SLOPE 0.2f

// ---- bf16 helpers (bit-level, RNE on pack, exact on unpack) ----
__device__ __forceinline__ unsigned short f2bf(float f) {
  unsigned int u = __float_as_uint(f);
  u += 0x7FFFu + ((u >> 16) & 1u);
  return (unsigned short)(u >> 16);
}
__device__ __forceinline__ float bf2f(unsigned short u) {
  return __uint_as_float((unsigned int)u << 16);
}

// denom = 0, deg = 0
__global__ void init_stats_kernel(float* __restrict__ denom, int* __restrict__ deg) {
  int i = blockIdx.x * blockDim.x + threadIdx.x;
  if (i < N_NODES) {
    denom[i] = 0.0f;
    deg[i] = 0;
  }
}

// dst-degree histogram
__global__ void count_deg_kernel(const int* __restrict__ dst, int* __restrict__ deg) {
  int i = blockIdx.x * blockDim.x + threadIdx.x;
  if (i < N_EDGES) atomicAdd(&deg[dst[i]], 1);
}

// Tiled GEMM: [ps|pt|fcp] = feat @ [Ws;Wt;Wfc]^T, fp32 compute, bf16 store.
// BM=BN=64, BK=32, 256 threads, 4x4 microtile/thread.
__global__ __launch_bounds__(256) void proj_gemm_kernel(
    const float* __restrict__ feat,
    const float* __restrict__ Ws,
    const float* __restrict__ Wt,
    const float* __restrict__ Wfc,
    unsigned short* __restrict__ ps, unsigned short* __restrict__ pt,
    unsigned short* __restrict__ fcp) {
  __shared__ float As[32][68];
  __shared__ float Bs[32][68];
  const int mt = blockIdx.x;
  const int nt = blockIdx.y;       // 0..11: 4 tiles each for Ws, Wt, Wfc
  const int tid = threadIdx.x;

  const float* W = (nt < 4) ? Ws : ((nt < 8) ? Wt : Wfc);
  unsigned short* outp = (nt < 4) ? ps : ((nt < 8) ? pt : fcp);
  const int ncol0 = (nt & 3) * 64;
  const int row0 = mt * 64;

  const int lrow = tid >> 3;          // 0..31
  const int lcol = (tid & 7) * 4;     // 0,4,...,28
  const int tx = tid & 15;
  const int ty = tid >> 4;
  float acc[4][4] = {{0.f}};

  for (int k0 = 0; k0 < D; k0 += 32) {
#pragma unroll
    for (int p = 0; p < 2; ++p) {
      const int r = lrow + p * 32;
      const int gr = row0 + r;
      float4 v = make_float4(0.f, 0.f, 0.f, 0.f);
      if (gr < N_NODES) v = *(const float4*)(feat + (size_t)gr * D + k0 + lcol);
      As[lcol + 0][r] = v.x; As[lcol + 1][r] = v.y;
      As[lcol + 2][r] = v.z; As[lcol + 3][r] = v.w;
      float4 w = *(const float4*)(W + (size_t)(ncol0 + r) * D + k0 + lcol);
      Bs[lcol + 0][r] = w.x; Bs[lcol + 1][r] = w.y;
      Bs[lcol + 2][r] = w.z; Bs[lcol + 3][r] = w.w;
    }
    __syncthreads();
#pragma unroll
    for (int k = 0; k < 32; ++k) {
      const float4 av = *(const float4*)&As[k][ty * 4];
      const float4 bv = *(const float4*)&Bs[k][tx * 4];
      acc[0][0] += av.x * bv.x; acc[0][1] += av.x * bv.y;
      acc[0][2] += av.x * bv.z; acc[0][3] += av.x * bv.w;
      acc[1][0] += av.y * bv.x; acc[1][1] += av.y * bv.y;
      acc[1][2] += av.y * bv.z; acc[1][3] += av.y * bv.w;
      acc[2][0] += av.z * bv.x; acc[2][1] += av.z * bv.y;
      acc[2][2] += av.z * bv.z; acc[2][3] += av.z * bv.w;
      acc[3][0] += av.w * bv.x; acc[3][1] += av.w * bv.y;
      acc[3][2] += av.w * bv.z; acc[3][3] += av.w * bv.w;
    }
    __syncthreads();
  }

#pragma unroll
  for (int i = 0; i < 4; ++i) {
    const int gr = row0 + ty * 4 + i;
    if (gr < N_NODES) {
      ushort4 v;
      v.x = f2bf(acc[i][0]); v.y = f2bf(acc[i][1]);
      v.z = f2bf(acc[i][2]); v.w = f2bf(acc[i][3]);
      *(ushort4*)(outp + (size_t)gr * D + ncol0 + tx * 4) = v;
    }
  }
}

// Single-block exclusive scan of deg[10000] -> ofs[10001], cursor = ofs.
#define SCAN_T 256
#define CHUNK 40   // 256*40 = 10240 >= N_NODES
__global__ __launch_bounds__(SCAN_T) void scan_kernel(const int* __restrict__ deg,
                                                      int* __restrict__ ofs,
                                                      int* __restrict__ cursor) {
  __shared__ int sv[N_NODES];
  __shared__ int part[SCAN_T];
  const int t = threadIdx.x;
  for (int i = t; i < N_NODES; i += SCAN_T) sv[i] = deg[i];
  __syncthreads();
  const int base = t * CHUNK;
  int sum = 0;
#pragma unroll
  for (int i = 0; i < CHUNK; ++i) {
    int idx = base + i;
    if (idx < N_NODES) {
      int v = sv[idx];
      sv[idx] = sum;     // chunk-exclusive
      sum += v;
    }
  }
  part[t] = sum;
  __syncthreads();
  for (int off = 1; off < SCAN_T; off <<= 1) {
    int v = (t >= off) ? part[t - off] : 0;
    __syncthreads();
    part[t] += v;
    __syncthreads();
  }
  for (int i = t; i < N_NODES; i += SCAN_T) {
    int c = i / CHUNK;
    int o = sv[i] + (c ? part[c - 1] : 0);
    ofs[i] = o;
    cursor[i] = o;
  }
  if (t == 0) ofs[N_NODES] = part[SCAN_T - 1];
}

// Bucket edges by dst (index-only).
__global__ void fill_kernel(const int* __restrict__ src,
                            const int* __restrict__ dst,
                            int* __restrict__ cursor,
                            int* __restrict__ src_b) {
  const int i = blockIdx.x * blockDim.x + threadIdx.x;
  if (i >= N_EDGES) return;
  const int p = atomicAdd(&cursor[dst[i]], 1);
  src_b[p] = src[i];
}

// Block per dst node (4 waves, wave per edge). pt[dst] and Wattn are
// loop-invariant per-lane registers. expv = exp(e) (no max pass; |e| ~ O(5)
// for unit-scale inputs, mathematically identical after normalization).
__global__ __launch_bounds__(256) void logit_bucket_kernel(
    const unsigned short* __restrict__ ps,
    const unsigned short* __restrict__ pt,
    const int* __restrict__ src_b,
    const int* __restrict__ ofs,
    const float* __restrict__ Wattn,
    float* __restrict__ expv_b,
    float* __restrict__ denom) {
  const int n = blockIdx.x;
  const int beg = ofs[n], end = ofs[n + 1];
  if (beg == end) return;
  const int wave = threadIdx.x >> 6;
  const int lane = threadIdx.x & 63;

  ushort4 bu = *(const ushort4*)(pt + (size_t)n * D + lane * 4);
  const float4 b = make_float4(bf2f(bu.x), bf2f(bu.y), bf2f(bu.z), bf2f(bu.w));
  const float4 w = *(const float4*)(Wattn + lane * 4);

  for (int j = beg + wave; j < end; j += 4) {
    const int s = src_b[j];
    ushort4 au = *(const ushort4*)(ps + (size_t)s * D + lane * 4);
    float sum = 0.f, z;
    z = bf2f(au.x) + b.x; z = (z >= 0.f) ? z : NEG_SLOPE * z; sum += w.x * z;
    z = bf2f(au.y) + b.y; z = (z >= 0.f) ? z : NEG_SLOPE * z; sum += w.y * z;
    z = bf2f(au.z) + b.z; z = (z >= 0.f) ? z : NEG_SLOPE * z; sum += w.z * z;
    z = bf2f(au.w) + b.w; z = (z >= 0.f) ? z : NEG_SLOPE * z; sum += w.w * z;
#pragma unroll
    for (int off = 32; off > 0; off >>= 1) sum += __shfl_down(sum, off, 64);
    if (lane == 0) {
      float ex = __expf(sum);
      expv_b[j] = ex;
      atomicAdd(&denom[s], ex);
    }
  }
}

// One wave per dst node; lane owns dims [4*lane, 4*lane+4). Single write,
// fused bias. alpha computed inline (broadcast loads of expv/denom).
__global__ __launch_bounds__(64) void gather_agg_kernel(
    const unsigned short* __restrict__ fcp,
    const int* __restrict__ src_b,
    const float* __restrict__ expv_b,
    const float* __restrict__ denom,
    const int* __restrict__ ofs,
    const float* __restrict__ b_fc,
    float* __restrict__ out) {
  const int n = blockIdx.x;
  const int lane = threadIdx.x;
  const int beg = ofs[n], end = ofs[n + 1];
  float4 acc = make_float4(0.f, 0.f, 0.f, 0.f);
  for (int j = beg; j < end; ++j) {
    const int s = src_b[j];
    const float a = expv_b[j] / denom[s];
    ushort4 fu = *(const ushort4*)(fcp + (size_t)s * D + lane * 4);
    acc.x += a * bf2f(fu.x);
    acc.y += a * bf2f(fu.y);
    acc.z += a * bf2f(fu.z);
    acc.w += a * bf2f(fu.w);
  }
  const float4 bias = *(const float4*)(b_fc + lane * 4);
  acc.x += bias.x; acc.y += bias.y; acc.z += bias.z; acc.w += bias.w;
  *(float4*)(out + (size_t)n * D + lane * 4) = acc;
}

extern "C" void kernel_launch(void* const* d_in, const int* in_sizes, int n_in,
                              void* d_out, int out_size, void* d_ws, size_t ws_size,
                              hipStream_t stream) {
  const float* feat  = (const float*)d_in[0];
  const int*   src   = (const int*)d_in[1];
  const int*   dst   = (const int*)d_in[2];
  const float* Ws    = (const float*)d_in[3];
  const float* Wt    = (const float*)d_in[4];
  const float* Wattn = (const float*)d_in[5];
  const float* Wfc   = (const float*)d_in[6];
  const float* bfc   = (const float*)d_in[7];
  float* out = (float*)d_out;

  // workspace layout:
  // ps|pt|fcp (bf16, N*D each) | expv_b | denom (f32) | src_b|deg|ofs|cursor (i32)
  unsigned short* ps  = (unsigned short*)d_ws;
  unsigned short* pt  = ps + (size_t)N_NODES * D;
  unsigned short* fcp = pt + (size_t)N_NODES * D;
  float* expv_b = (float*)(fcp + (size_t)N_NODES * D);
  float* denom  = expv_b + N_EDGES;
  int*   src_b  = (int*)(denom + N_NODES);
  int*   deg    = src_b + N_EDGES;
  int*   ofs    = deg + N_NODES;      // N_NODES+1
  int*   cursor = ofs + N_NODES + 1;

  init_stats_kernel<<<(N_NODES + 255) / 256, 256, 0, stream>>>(denom, deg);
  count_deg_kernel<<<(N_EDGES + 255) / 256, 256, 0, stream>>>(dst, deg);
  dim3 pg((N_NODES + 63) / 64, 12);
  proj_gemm_kernel<<<pg, 256, 0, stream>>>(feat, Ws, Wt, Wfc, ps, pt, fcp);
  scan_kernel<<<1, SCAN_T, 0, stream>>>(deg, ofs, cursor);
  fill_kernel<<<(N_EDGES + 255) / 256, 256, 0, stream>>>(src, dst, cursor, src_b);
  logit_bucket_kernel<<<N_NODES, 256, 0, stream>>>(ps, pt, src_b, ofs, Wattn, expv_b, denom);
  gather_agg_kernel<<<N_NODES, 64, 0, stream>>>(fcp, src_b, expv_b, denom, ofs, bfc, out);
}

// Round 5
// 243.971 us; speedup vs baseline: 11.3788x; 1.1084x over previous
//
#include <hip/hip_runtime.h>
#include <math.h>

#define N_NODES 10000
#define N_EDGES 320000
#define D 256
#define NEG_SLOPE 0.2f

typedef unsigned short ushortT;
typedef __attribute__((ext_vector_type(8))) short bf16x8;   // 8 bf16 in 4 VGPRs
typedef __attribute__((ext_vector_type(4))) float f32x4;

// ---- bf16 helpers (bit-level, RNE on pack, exact on unpack) ----
__device__ __forceinline__ unsigned short f2bf(float f) {
  unsigned int u = __float_as_uint(f);
  u += 0x7FFFu + ((u >> 16) & 1u);
  return (unsigned short)(u >> 16);
}
__device__ __forceinline__ float bf2f(unsigned short u) {
  return __uint_as_float((unsigned int)u << 16);
}

// denom = 0, deg = 0
__global__ void init_stats_kernel(float* __restrict__ denom, int* __restrict__ deg) {
  int i = blockIdx.x * blockDim.x + threadIdx.x;
  if (i < N_NODES) {
    denom[i] = 0.0f;
    deg[i] = 0;
  }
}

// dst-degree histogram
__global__ void count_deg_kernel(const int* __restrict__ dst, int* __restrict__ deg) {
  int i = blockIdx.x * blockDim.x + threadIdx.x;
  if (i < N_EDGES) atomicAdd(&deg[dst[i]], 1);
}

// Cast feat -> featb (bf16) and Ws|Wt|Wfc -> Wcat[768][256] (bf16), float4-wise.
#define NF4 (N_NODES * D / 4)   // 640000
#define NW4 (256 * 256 / 4)     // 16384
__global__ void cast_bf16_kernel(const float* __restrict__ feat,
                                 const float* __restrict__ Ws,
                                 const float* __restrict__ Wt,
                                 const float* __restrict__ Wfc,
                                 ushortT* __restrict__ featb,
                                 ushortT* __restrict__ Wcat) {
  const int g = blockIdx.x * blockDim.x + threadIdx.x;
  if (g < NF4) {
    float4 v = ((const float4*)feat)[g];
    ushort4 u;
    u.x = f2bf(v.x); u.y = f2bf(v.y); u.z = f2bf(v.z); u.w = f2bf(v.w);
    ((ushort4*)featb)[g] = u;
  } else {
    const int gi = g - NF4;
    if (gi < 3 * NW4) {
      const float* W = (gi < NW4) ? Ws : ((gi < 2 * NW4) ? Wt : Wfc);
      const int off = gi - ((gi < NW4) ? 0 : ((gi < 2 * NW4) ? NW4 : 2 * NW4));
      float4 v = ((const float4*)W)[off];
      ushort4 u;
      u.x = f2bf(v.x); u.y = f2bf(v.y); u.z = f2bf(v.z); u.w = f2bf(v.w);
      ((ushort4*)Wcat)[gi] = u;
    }
  }
}

// MFMA projection: [ps|pt|fcp] = feat @ Wcat^T  (bf16 in, fp32 acc, bf16 out)
// Block: 64x64 output tile, 4 waves, wave = 32x32 (2x2 mfma_f32_16x16x32_bf16).
// Fragments loaded DIRECTLY from global (no LDS): A rows L1-resident,
// Wcat (384 KB) L2-resident.
__global__ __launch_bounds__(256) void proj_mfma_kernel(
    const ushortT* __restrict__ featb,
    const ushortT* __restrict__ Wcat,
    ushortT* __restrict__ ps, ushortT* __restrict__ pt,
    ushortT* __restrict__ fcp) {
  const int m0 = blockIdx.x * 64;
  const int by = blockIdx.y;            // 0..11
  ushortT* outp = (by < 4) ? ps : ((by < 8) ? pt : fcp);
  const int col0 = (by & 3) * 64;       // column base within the 256-col output
  const int n0 = by * 64;               // row base within Wcat

  const int wave = threadIdx.x >> 6;
  const int lane = threadIdx.x & 63;
  const int quad = lane >> 4;
  const int l16 = lane & 15;

  const int m_base = m0 + (wave & 1) * 32;
  const int wn = wave >> 1;             // 0..1
  const int nb = n0 + wn * 32;          // Wcat row base for this wave

  f32x4 acc[2][2];
#pragma unroll
  for (int i = 0; i < 2; ++i)
#pragma unroll
    for (int j = 0; j < 2; ++j) acc[i][j] = (f32x4){0.f, 0.f, 0.f, 0.f};

  const bf16x8 zero = {0, 0, 0, 0, 0, 0, 0, 0};
  const int r0 = m_base + l16;
  const int r1 = r0 + 16;

#pragma unroll
  for (int k0 = 0; k0 < D; k0 += 32) {
    const int ko = k0 + quad * 8;
    bf16x8 a0 = (r0 < N_NODES) ? *(const bf16x8*)(featb + (size_t)r0 * D + ko) : zero;
    bf16x8 a1 = (r1 < N_NODES) ? *(const bf16x8*)(featb + (size_t)r1 * D + ko) : zero;
    bf16x8 b0 = *(const bf16x8*)(Wcat + (size_t)(nb + l16) * D + ko);
    bf16x8 b1 = *(const bf16x8*)(Wcat + (size_t)(nb + 16 + l16) * D + ko);
    acc[0][0] = __builtin_amdgcn_mfma_f32_16x16x32_bf16(a0, b0, acc[0][0], 0, 0, 0);
    acc[0][1] = __builtin_amdgcn_mfma_f32_16x16x32_bf16(a0, b1, acc[0][1], 0, 0, 0);
    acc[1][0] = __builtin_amdgcn_mfma_f32_16x16x32_bf16(a1, b0, acc[1][0], 0, 0, 0);
    acc[1][1] = __builtin_amdgcn_mfma_f32_16x16x32_bf16(a1, b1, acc[1][1], 0, 0, 0);
  }

  // C/D layout: col = lane&15, row = quad*4 + reg  [verified m89/m91]
#pragma unroll
  for (int mi = 0; mi < 2; ++mi) {
#pragma unroll
    for (int r = 0; r < 4; ++r) {
      const int row = m_base + mi * 16 + quad * 4 + r;
      if (row < N_NODES) {
#pragma unroll
        for (int ni = 0; ni < 2; ++ni) {
          const int col = col0 + wn * 32 + ni * 16 + l16;
          outp[(size_t)row * D + col] = f2bf(acc[mi][ni][r]);
        }
      }
    }
  }
}

// Single-block exclusive scan of deg[10000] -> ofs[10001], cursor = ofs.
#define SCAN_T 256
#define CHUNK 40   // 256*40 = 10240 >= N_NODES
__global__ __launch_bounds__(SCAN_T) void scan_kernel(const int* __restrict__ deg,
                                                      int* __restrict__ ofs,
                                                      int* __restrict__ cursor) {
  __shared__ int sv[N_NODES];
  __shared__ int part[SCAN_T];
  const int t = threadIdx.x;
  for (int i = t; i < N_NODES; i += SCAN_T) sv[i] = deg[i];
  __syncthreads();
  const int base = t * CHUNK;
  int sum = 0;
#pragma unroll
  for (int i = 0; i < CHUNK; ++i) {
    int idx = base + i;
    if (idx < N_NODES) {
      int v = sv[idx];
      sv[idx] = sum;     // chunk-exclusive
      sum += v;
    }
  }
  part[t] = sum;
  __syncthreads();
  for (int off = 1; off < SCAN_T; off <<= 1) {
    int v = (t >= off) ? part[t - off] : 0;
    __syncthreads();
    part[t] += v;
    __syncthreads();
  }
  for (int i = t; i < N_NODES; i += SCAN_T) {
    int c = i / CHUNK;
    int o = sv[i] + (c ? part[c - 1] : 0);
    ofs[i] = o;
    cursor[i] = o;
  }
  if (t == 0) ofs[N_NODES] = part[SCAN_T - 1];
}

// Bucket edges by dst (index-only).
__global__ void fill_kernel(const int* __restrict__ src,
                            const int* __restrict__ dst,
                            int* __restrict__ cursor,
                            int* __restrict__ src_b) {
  const int i = blockIdx.x * blockDim.x + threadIdx.x;
  if (i >= N_EDGES) return;
  const int p = atomicAdd(&cursor[dst[i]], 1);
  src_b[p] = src[i];
}

// Block per dst node (4 waves, wave per edge). pt[dst] and Wattn held in
// registers. expv = exp(e) (no max pass; |e| small for unit-scale inputs,
// identical after normalization).
__global__ __launch_bounds__(256) void logit_bucket_kernel(
    const ushortT* __restrict__ ps,
    const ushortT* __restrict__ pt,
    const int* __restrict__ src_b,
    const int* __restrict__ ofs,
    const float* __restrict__ Wattn,
    float* __restrict__ expv_b,
    float* __restrict__ denom) {
  const int n = blockIdx.x;
  const int beg = ofs[n], end = ofs[n + 1];
  if (beg == end) return;
  const int wave = threadIdx.x >> 6;
  const int lane = threadIdx.x & 63;

  ushort4 bu = *(const ushort4*)(pt + (size_t)n * D + lane * 4);
  const float4 b = make_float4(bf2f(bu.x), bf2f(bu.y), bf2f(bu.z), bf2f(bu.w));
  const float4 w = *(const float4*)(Wattn + lane * 4);

  for (int j = beg + wave; j < end; j += 4) {
    const int s = src_b[j];
    ushort4 au = *(const ushort4*)(ps + (size_t)s * D + lane * 4);
    float sum = 0.f, z;
    z = bf2f(au.x) + b.x; z = (z >= 0.f) ? z : NEG_SLOPE * z; sum += w.x * z;
    z = bf2f(au.y) + b.y; z = (z >= 0.f) ? z : NEG_SLOPE * z; sum += w.y * z;
    z = bf2f(au.z) + b.z; z = (z >= 0.f) ? z : NEG_SLOPE * z; sum += w.z * z;
    z = bf2f(au.w) + b.w; z = (z >= 0.f) ? z : NEG_SLOPE * z; sum += w.w * z;
#pragma unroll
    for (int off = 32; off > 0; off >>= 1) sum += __shfl_down(sum, off, 64);
    if (lane == 0) {
      float ex = __expf(sum);
      expv_b[j] = ex;
      atomicAdd(&denom[s], ex);
    }
  }
}

// One wave per dst node; lane owns dims [4*lane, 4*lane+4). Single write,
// fused bias.
__global__ __launch_bounds__(64) void gather_agg_kernel(
    const ushortT* __restrict__ fcp,
    const int* __restrict__ src_b,
    const float* __restrict__ expv_b,
    const float* __restrict__ denom,
    const int* __restrict__ ofs,
    const float* __restrict__ b_fc,
    float* __restrict__ out) {
  const int n = blockIdx.x;
  const int lane = threadIdx.x;
  const int beg = ofs[n], end = ofs[n + 1];
  float4 acc = make_float4(0.f, 0.f, 0.f, 0.f);
  for (int j = beg; j < end; ++j) {
    const int s = src_b[j];
    const float a = expv_b[j] / denom[s];
    ushort4 fu = *(const ushort4*)(fcp + (size_t)s * D + lane * 4);
    acc.x += a * bf2f(fu.x);
    acc.y += a * bf2f(fu.y);
    acc.z += a * bf2f(fu.z);
    acc.w += a * bf2f(fu.w);
  }
  const float4 bias = *(const float4*)(b_fc + lane * 4);
  acc.x += bias.x; acc.y += bias.y; acc.z += bias.z; acc.w += bias.w;
  *(float4*)(out + (size_t)n * D + lane * 4) = acc;
}

extern "C" void kernel_launch(void* const* d_in, const int* in_sizes, int n_in,
                              void* d_out, int out_size, void* d_ws, size_t ws_size,
                              hipStream_t stream) {
  const float* feat  = (const float*)d_in[0];
  const int*   src   = (const int*)d_in[1];
  const int*   dst   = (const int*)d_in[2];
  const float* Ws    = (const float*)d_in[3];
  const float* Wt    = (const float*)d_in[4];
  const float* Wattn = (const float*)d_in[5];
  const float* Wfc   = (const float*)d_in[6];
  const float* bfc   = (const float*)d_in[7];
  float* out = (float*)d_out;

  // workspace layout:
  // ps|pt|fcp|featb (bf16, N*D each) | Wcat (bf16 768*256) |
  // expv_b | denom (f32) | src_b | deg | ofs | cursor (i32)
  ushortT* ps    = (ushortT*)d_ws;
  ushortT* pt    = ps + (size_t)N_NODES * D;
  ushortT* fcp   = pt + (size_t)N_NODES * D;
  ushortT* featb = fcp + (size_t)N_NODES * D;
  ushortT* Wcat  = featb + (size_t)N_NODES * D;
  float* expv_b  = (float*)(Wcat + (size_t)768 * 256);
  float* denom   = expv_b + N_EDGES;
  int*   src_b   = (int*)(denom + N_NODES);
  int*   deg     = src_b + N_EDGES;
  int*   ofs     = deg + N_NODES;      // N_NODES+1
  int*   cursor  = ofs + N_NODES + 1;

  init_stats_kernel<<<(N_NODES + 255) / 256, 256, 0, stream>>>(denom, deg);
  count_deg_kernel<<<(N_EDGES + 255) / 256, 256, 0, stream>>>(dst, deg);
  cast_bf16_kernel<<<(NF4 + 3 * NW4 + 255) / 256, 256, 0, stream>>>(
      feat, Ws, Wt, Wfc, featb, Wcat);
  dim3 pg((N_NODES + 63) / 64, 12);
  proj_mfma_kernel<<<pg, 256, 0, stream>>>(featb, Wcat, ps, pt, fcp);
  scan_kernel<<<1, SCAN_T, 0, stream>>>(deg, ofs, cursor);
  fill_kernel<<<(N_EDGES + 255) / 256, 256, 0, stream>>>(src, dst, cursor, src_b);
  logit_bucket_kernel<<<N_NODES, 256, 0, stream>>>(ps, pt, src_b, ofs, Wattn, expv_b, denom);
  gather_agg_kernel<<<N_NODES, 64, 0, stream>>>(fcp, src_b, expv_b, denom, ofs, bfc, out);
}

// Round 6
// 211.359 us; speedup vs baseline: 13.1345x; 1.1543x over previous
//
#include <hip/hip_runtime.h>
#include <math.h>

#define N_NODES 10000
#define N_EDGES 320000
#define D 256
#define NEG_SLOPE 0.2f

typedef unsigned short ushortT;
typedef __attribute__((ext_vector_type(8))) short bf16x8;   // 8 bf16 in 4 VGPRs
typedef __attribute__((ext_vector_type(4))) float f32x4;

// ---- bf16 helpers (bit-level, RNE on pack, exact on unpack) ----
__device__ __forceinline__ unsigned short f2bf(float f) {
  unsigned int u = __float_as_uint(f);
  u += 0x7FFFu + ((u >> 16) & 1u);
  return (unsigned short)(u >> 16);
}
__device__ __forceinline__ float bf2f(unsigned short u) {
  return __uint_as_float((unsigned int)u << 16);
}

// Fused: dst-degree histogram (deg pre-zeroed via memset) + bf16 casts.
#define NF4 (N_NODES * D / 4)   // 640000 float4s of feat
#define NW4 (256 * 256 / 4)     // 16384 float4s per W matrix
__global__ void prep_kernel(const int* __restrict__ dst,
                            const float* __restrict__ feat,
                            const float* __restrict__ Ws,
                            const float* __restrict__ Wt,
                            const float* __restrict__ Wfc,
                            int* __restrict__ deg,
                            ushortT* __restrict__ featb,
                            ushortT* __restrict__ Wcat) {
  const int g = blockIdx.x * blockDim.x + threadIdx.x;
  if (g < N_EDGES) {
    atomicAdd(&deg[dst[g]], 1);
    return;
  }
  const int g2 = g - N_EDGES;
  if (g2 < NF4) {
    float4 v = ((const float4*)feat)[g2];
    ushort4 u;
    u.x = f2bf(v.x); u.y = f2bf(v.y); u.z = f2bf(v.z); u.w = f2bf(v.w);
    ((ushort4*)featb)[g2] = u;
  } else {
    const int gi = g2 - NF4;
    if (gi < 3 * NW4) {
      const float* W = (gi < NW4) ? Ws : ((gi < 2 * NW4) ? Wt : Wfc);
      const int off = gi - ((gi < NW4) ? 0 : ((gi < 2 * NW4) ? NW4 : 2 * NW4));
      float4 v = ((const float4*)W)[off];
      ushort4 u;
      u.x = f2bf(v.x); u.y = f2bf(v.y); u.z = f2bf(v.z); u.w = f2bf(v.w);
      ((ushort4*)Wcat)[gi] = u;
    }
  }
}

// MFMA projection: [ps|pt|fcp] = feat @ Wcat^T  (bf16 in, fp32 acc, bf16 out)
// Block: 64x64 output tile, 4 waves, wave = 32x32 (2x2 mfma_f32_16x16x32_bf16).
// Fragments loaded DIRECTLY from global (no LDS): A rows L1-resident,
// Wcat (384 KB) L2-resident.
__global__ __launch_bounds__(256) void proj_mfma_kernel(
    const ushortT* __restrict__ featb,
    const ushortT* __restrict__ Wcat,
    ushortT* __restrict__ ps, ushortT* __restrict__ pt,
    ushortT* __restrict__ fcp) {
  const int m0 = blockIdx.x * 64;
  const int by = blockIdx.y;            // 0..11
  ushortT* outp = (by < 4) ? ps : ((by < 8) ? pt : fcp);
  const int col0 = (by & 3) * 64;
  const int n0 = by * 64;

  const int wave = threadIdx.x >> 6;
  const int lane = threadIdx.x & 63;
  const int quad = lane >> 4;
  const int l16 = lane & 15;

  const int m_base = m0 + (wave & 1) * 32;
  const int wn = wave >> 1;
  const int nb = n0 + wn * 32;

  f32x4 acc[2][2];
#pragma unroll
  for (int i = 0; i < 2; ++i)
#pragma unroll
    for (int j = 0; j < 2; ++j) acc[i][j] = (f32x4){0.f, 0.f, 0.f, 0.f};

  const bf16x8 zero = {0, 0, 0, 0, 0, 0, 0, 0};
  const int r0 = m_base + l16;
  const int r1 = r0 + 16;

#pragma unroll
  for (int k0 = 0; k0 < D; k0 += 32) {
    const int ko = k0 + quad * 8;
    bf16x8 a0 = (r0 < N_NODES) ? *(const bf16x8*)(featb + (size_t)r0 * D + ko) : zero;
    bf16x8 a1 = (r1 < N_NODES) ? *(const bf16x8*)(featb + (size_t)r1 * D + ko) : zero;
    bf16x8 b0 = *(const bf16x8*)(Wcat + (size_t)(nb + l16) * D + ko);
    bf16x8 b1 = *(const bf16x8*)(Wcat + (size_t)(nb + 16 + l16) * D + ko);
    acc[0][0] = __builtin_amdgcn_mfma_f32_16x16x32_bf16(a0, b0, acc[0][0], 0, 0, 0);
    acc[0][1] = __builtin_amdgcn_mfma_f32_16x16x32_bf16(a0, b1, acc[0][1], 0, 0, 0);
    acc[1][0] = __builtin_amdgcn_mfma_f32_16x16x32_bf16(a1, b0, acc[1][0], 0, 0, 0);
    acc[1][1] = __builtin_amdgcn_mfma_f32_16x16x32_bf16(a1, b1, acc[1][1], 0, 0, 0);
  }

  // C/D layout: col = lane&15, row = quad*4 + reg  [verified m89/m91]
#pragma unroll
  for (int mi = 0; mi < 2; ++mi) {
#pragma unroll
    for (int r = 0; r < 4; ++r) {
      const int row = m_base + mi * 16 + quad * 4 + r;
      if (row < N_NODES) {
#pragma unroll
        for (int ni = 0; ni < 2; ++ni) {
          const int col = col0 + wn * 32 + ni * 16 + l16;
          outp[(size_t)row * D + col] = f2bf(acc[mi][ni][r]);
        }
      }
    }
  }
}

// Single-block exclusive scan of deg[10000] -> ofs[10001], cursor = ofs.
#define SCAN_T 256
#define CHUNK 40   // 256*40 = 10240 >= N_NODES
__global__ __launch_bounds__(SCAN_T) void scan_kernel(const int* __restrict__ deg,
                                                      int* __restrict__ ofs,
                                                      int* __restrict__ cursor) {
  __shared__ int sv[N_NODES];
  __shared__ int part[SCAN_T];
  const int t = threadIdx.x;
  for (int i = t; i < N_NODES; i += SCAN_T) sv[i] = deg[i];
  __syncthreads();
  const int base = t * CHUNK;
  int sum = 0;
#pragma unroll
  for (int i = 0; i < CHUNK; ++i) {
    int idx = base + i;
    if (idx < N_NODES) {
      int v = sv[idx];
      sv[idx] = sum;     // chunk-exclusive
      sum += v;
    }
  }
  part[t] = sum;
  __syncthreads();
  for (int off = 1; off < SCAN_T; off <<= 1) {
    int v = (t >= off) ? part[t - off] : 0;
    __syncthreads();
    part[t] += v;
    __syncthreads();
  }
  for (int i = t; i < N_NODES; i += SCAN_T) {
    int c = i / CHUNK;
    int o = sv[i] + (c ? part[c - 1] : 0);
    ofs[i] = o;
    cursor[i] = o;
  }
  if (t == 0) ofs[N_NODES] = part[SCAN_T - 1];
}

// Bucket edges by dst (index-only).
__global__ void fill_kernel(const int* __restrict__ src,
                            const int* __restrict__ dst,
                            int* __restrict__ cursor,
                            int* __restrict__ src_b) {
  const int i = blockIdx.x * blockDim.x + threadIdx.x;
  if (i >= N_EDGES) return;
  const int p = atomicAdd(&cursor[dst[i]], 1);
  src_b[p] = src[i];
}

// Block per dst node: 4 waves, each wave processes 2 edges at a time
// (32-lane half-wave per edge, bf16x8 = 16 B/lane; 32 lanes cover all 256
// dims). Width-32 shuffle reduce (5 steps, shared by both halves). pt[dst]
// and Wattn held in registers. expv = exp(e) (no max pass; |e| small for
// unit-scale inputs, identical after normalization).
__global__ __launch_bounds__(256) void logit_bucket_kernel(
    const ushortT* __restrict__ ps,
    const ushortT* __restrict__ pt,
    const int* __restrict__ src_b,
    const int* __restrict__ ofs,
    const float* __restrict__ Wattn,
    float* __restrict__ expv_b,
    float* __restrict__ denom) {
  const int n = blockIdx.x;
  const int beg = ofs[n], end = ofs[n + 1];
  if (beg == end) return;
  const int wave = threadIdx.x >> 6;
  const int lane = threadIdx.x & 63;
  const int half = lane >> 5;     // which edge of the pair
  const int l32 = lane & 31;      // dim group: dims [l32*8, l32*8+8)

  bf16x8 bu = *(const bf16x8*)(pt + (size_t)n * D + l32 * 8);
  float b[8], w[8];
  const float4 w0 = *(const float4*)(Wattn + l32 * 8);
  const float4 w1 = *(const float4*)(Wattn + l32 * 8 + 4);
  w[0] = w0.x; w[1] = w0.y; w[2] = w0.z; w[3] = w0.w;
  w[4] = w1.x; w[5] = w1.y; w[6] = w1.z; w[7] = w1.w;
#pragma unroll
  for (int i = 0; i < 8; ++i) b[i] = bf2f((unsigned short)bu[i]);

#pragma unroll 2
  for (int j = beg + wave * 2 + half; j < end; j += 8) {
    const int s = src_b[j];
    bf16x8 au = *(const bf16x8*)(ps + (size_t)s * D + l32 * 8);
    float sum = 0.f;
#pragma unroll
    for (int i = 0; i < 8; ++i) {
      float z = bf2f((unsigned short)au[i]) + b[i];
      z = fmaxf(z, NEG_SLOPE * z);
      sum = fmaf(w[i], z, sum);
    }
#pragma unroll
    for (int off = 16; off > 0; off >>= 1) sum += __shfl_down(sum, off, 32);
    if (l32 == 0) {
      float ex = __expf(sum);
      expv_b[j] = ex;
      atomicAdd(&denom[s], ex);
    }
  }
}

// Block per dst node: 4 waves x 2 half-waves = 8 concurrent edge chains,
// bf16x8 gathers of fcp[src], partials combined via LDS, fused bias,
// single coalesced fp32 write.
__global__ __launch_bounds__(256) void gather_agg_kernel(
    const ushortT* __restrict__ fcp,
    const int* __restrict__ src_b,
    const float* __restrict__ expv_b,
    const float* __restrict__ denom,
    const int* __restrict__ ofs,
    const float* __restrict__ b_fc,
    float* __restrict__ out) {
  __shared__ float red[8][D];   // 8 KB
  const int n = blockIdx.x;
  const int tid = threadIdx.x;
  const int wave = tid >> 6;
  const int lane = tid & 63;
  const int half = lane >> 5;
  const int l32 = lane & 31;
  const int grp = wave * 2 + half;   // 0..7
  const int beg = ofs[n], end = ofs[n + 1];

  float acc[8];
#pragma unroll
  for (int i = 0; i < 8; ++i) acc[i] = 0.f;

#pragma unroll 2
  for (int j = beg + grp; j < end; j += 8) {
    const int s = src_b[j];
    const float a = expv_b[j] / denom[s];
    bf16x8 fu = *(const bf16x8*)(fcp + (size_t)s * D + l32 * 8);
#pragma unroll
    for (int i = 0; i < 8; ++i)
      acc[i] = fmaf(a, bf2f((unsigned short)fu[i]), acc[i]);
  }
  float4 v0 = make_float4(acc[0], acc[1], acc[2], acc[3]);
  float4 v1 = make_float4(acc[4], acc[5], acc[6], acc[7]);
  *(float4*)&red[grp][l32 * 8] = v0;
  *(float4*)&red[grp][l32 * 8 + 4] = v1;
  __syncthreads();
  float o = b_fc[tid];
#pragma unroll
  for (int g = 0; g < 8; ++g) o += red[g][tid];
  out[(size_t)n * D + tid] = o;
}

extern "C" void kernel_launch(void* const* d_in, const int* in_sizes, int n_in,
                              void* d_out, int out_size, void* d_ws, size_t ws_size,
                              hipStream_t stream) {
  const float* feat  = (const float*)d_in[0];
  const int*   src   = (const int*)d_in[1];
  const int*   dst   = (const int*)d_in[2];
  const float* Ws    = (const float*)d_in[3];
  const float* Wt    = (const float*)d_in[4];
  const float* Wattn = (const float*)d_in[5];
  const float* Wfc   = (const float*)d_in[6];
  const float* bfc   = (const float*)d_in[7];
  float* out = (float*)d_out;

  // workspace layout:
  // ps|pt|fcp|featb (bf16, N*D each) | Wcat (bf16 768*256) |
  // expv_b (f32) | denom (f32) | deg (i32) | src_b | ofs | cursor (i32)
  ushortT* ps    = (ushortT*)d_ws;
  ushortT* pt    = ps + (size_t)N_NODES * D;
  ushortT* fcp   = pt + (size_t)N_NODES * D;
  ushortT* featb = fcp + (size_t)N_NODES * D;
  ushortT* Wcat  = featb + (size_t)N_NODES * D;
  float* expv_b  = (float*)(Wcat + (size_t)768 * 256);
  float* denom   = expv_b + N_EDGES;
  int*   deg     = (int*)(denom + N_NODES);
  int*   src_b   = deg + N_NODES;
  int*   ofs     = src_b + N_EDGES;    // N_NODES+1
  int*   cursor  = ofs + N_NODES + 1;

  // zero denom (fp32 0.0 == all-zero bytes) and deg in one async memset
  hipMemsetAsync(denom, 0, 2 * N_NODES * sizeof(float), stream);
  prep_kernel<<<(N_EDGES + NF4 + 3 * NW4 + 255) / 256, 256, 0, stream>>>(
      dst, feat, Ws, Wt, Wfc, deg, featb, Wcat);
  scan_kernel<<<1, SCAN_T, 0, stream>>>(deg, ofs, cursor);
  fill_kernel<<<(N_EDGES + 255) / 256, 256, 0, stream>>>(src, dst, cursor, src_b);
  dim3 pg((N_NODES + 63) / 64, 12);
  proj_mfma_kernel<<<pg, 256, 0, stream>>>(featb, Wcat, ps, pt, fcp);
  logit_bucket_kernel<<<N_NODES, 256, 0, stream>>>(ps, pt, src_b, ofs, Wattn, expv_b, denom);
  gather_agg_kernel<<<N_NODES, 256, 0, stream>>>(fcp, src_b, expv_b, denom, ofs, bfc, out);
}